// Round 2
// baseline (858.376 us; speedup 1.0000x reference)
//
#include <hip/hip_runtime.h>
#include <hip/hip_bf16.h>

// Problem constants
#define NNEUR 8192
#define NCONV 64
#define LYC   36
#define LXC   36
#define BATCH 256
#define KRAW  1296   // 36*36
#define KPAD  1344   // 21*64
#define KITER 21     // KPAD/64
#define MROWS 16384  // BATCH*NCONV
#define BM 256
#define BN 256
#define BK 64
// One K-tile image per operand per iter: 2048 chunks of 16B = 32 KB.
#define A_IT_H   16384                 // halfs per (tile, it)
#define A_TILE_H (KITER * A_IT_H)      // 344064 halfs = 672 KB
#define B_TILE_H (KITER * A_IT_H)      // same (256-row n-tiles)

typedef __attribute__((ext_vector_type(8))) _Float16 half8;
typedef __attribute__((ext_vector_type(4))) float f32x4;
typedef __attribute__((ext_vector_type(16))) float f32x16;

__device__ __forceinline__ void async_copy16(const void* g, void* l) {
  __builtin_amdgcn_global_load_lds(
      (const __attribute__((address_space(1))) void*)g,
      (__attribute__((address_space(3))) void*)l, 16, 0, 0);
}

// Prep: emit A (conv->f16) in the GEMM's staged LDS-image order with the
// bank-XOR swizzle baked in (A goes through LDS). B (Wy*Wx*256->f16) is
// consumed DIRECT global->VGPR by the GEMM, so it is stored UNswizzled:
// within a BK=64 row, chunk c at slot c.
// grid: x = 0..167 -> A (it = x>>3, i = x&7, mtile = y);
//       x = 168..251 -> B (x'=x-168, it = x'>>2, i4 = x'&3,
//                          ntile = y>>1, row-half = y&1).
__global__ __launch_bounds__(256) void prep_kernel(
    const float* __restrict__ conv, const float* __restrict__ Wy,
    const float* __restrict__ Wx, _Float16* __restrict__ A,
    _Float16* __restrict__ B) {
  const int t = threadIdx.x;
  const int bx = blockIdx.x;
  const int slot = t & 7;
  half8 h;
  if (bx < 168) {  // A part (swizzled image, unchanged)
    const int tile = blockIdx.y;
    const int it = bx >> 3, i = bx & 7;
    const int r = (t >> 3) + 32 * i;                 // row in tile, 0..255
    const int c = (slot - r) & 7;                    // source chunk
    const int k0 = it * 64 + c * 8;
    const int grow = tile * BM + r;
    if (k0 < KRAW) {
      const float* s = conv + (size_t)grow * KRAW + k0;
#pragma unroll
      for (int e = 0; e < 8; e++) h[e] = (_Float16)s[e];
    } else {
#pragma unroll
      for (int e = 0; e < 8; e++) h[e] = (_Float16)0.f;
    }
    *(half8*)(A + (size_t)tile * A_TILE_H + ((size_t)bx * 256 + t) * 8) = h;
  } else {  // B part: 256-row n-tiles, UNswizzled chunk order
    const int bxp = bx - 168;                        // 0..83
    const int it = bxp >> 2, i4 = bxp & 3;           // it 0..20
    const int yb = blockIdx.y & 1;
    const int ntile = blockIdx.y >> 1;               // 0..31
    const int r = (t >> 3) + 32 * i4 + 128 * yb;     // row in tile, 0..255
    const int k0 = it * 64 + slot * 8;               // chunk c == slot
    const int n = ntile * BN + r;
#pragma unroll
    for (int e = 0; e < 8; e++) {
      const int k = k0 + e;
      float v = 0.f;
      if (k < KRAW) {
        const int y = k / LXC;
        const int x = k - y * LXC;
        v = Wy[n * LYC + y] * Wx[n * LXC + x] * 256.f;
      }
      h[e] = (_Float16)v;
    }
    // staged position p = r*8 + slot, == yb*1024 + i4*256 + t
    *(half8*)(B + (size_t)ntile * B_TILE_H + (size_t)it * A_IT_H +
              (size_t)(yb * 1024 + i4 * 256 + t) * 8) = h;
  }
}

// Fused GEMM, A-through-LDS + B-direct-to-register.
// Block tile 256(M)x256(N), BK=64, 8 waves as 4(M)x2(N); wave tile 64x128
// = [2 mb][4 nb] of 32x32x16 f16 MFMA (acc 8 x f32x16 = 128 AGPR).
// LDS = A only, 2 x 32 KB double buffer. B fragments are loaded directly
// from the staged global image into VGPRs, pipelined one ks-step ahead
// (B panel is L2-resident: 4 ntiles per XCD = 2.7 MB < 4 MB L2).
// Per block-iter pipe budget: MFMA 2163 cy > LDS ~1400 cy > L2 ~1150 cy.
__global__ __launch_bounds__(512, 2) void gemm_fused_kernel(
    const _Float16* __restrict__ A, const _Float16* __restrict__ B,
    const float* __restrict__ Wc, const float* __restrict__ bias,
    float* __restrict__ out) {
  __shared__ _Float16 As[2][BM * BK];  // 2 x 32 KB

  // XCD swizzle (bid&7 = XCD): each XCD owns 4 ntiles x all 64 mtiles,
  // ntile varies fastest so the ~32 co-resident blocks per XCD share
  // ~8 A-tiles (streamed) and keep the 2.7 MB B panel L2-resident.
  const int bid = blockIdx.x;              // 0..2047
  const int xcd = bid & 7, local = bid >> 3;
  const int ntile = xcd * 4 + (local & 3); // 0..31
  const int mtile = local >> 2;            // 0..63
  const int tileN = ntile * BN;

  const int t = threadIdx.x;
  const int lane = t & 63;
  const int wave = t >> 6;
  const int wm = wave >> 1, wn = wave & 1;  // 4x2 waves; wave tile 64x128
  const int r32 = lane & 31, hh = lane >> 5;

  f32x16 acc[2][4] = {};  // [mb][nb]

  const _Float16* pA = A + (size_t)mtile * A_TILE_H + t * 8;
  const _Float16* pB = B + (size_t)ntile * B_TILE_H;

  auto stage = [&](int b, int it) {
    const _Float16* sA = pA + it * A_IT_H;
    _Float16* lA = &As[b][t * 8];
#pragma unroll
    for (int i = 0; i < 4; i++) async_copy16(sA + i * 4096, lA + i * 4096);
  };

  half8 bq[2][4];  // double-buffered B fragments, [phase][nb]
  auto loadB = [&](half8* dst, int it, int ks) {
    const int cc = 2 * ks + hh;
    const _Float16* base = pB + (size_t)it * A_IT_H;
#pragma unroll
    for (int nb = 0; nb < 4; nb++) {
      const int rb = wn * 128 + nb * 32 + r32;
      dst[nb] = *(const half8*)(base + (rb * 8 + cc) * 8);
    }
  };

  stage(0, 0);
  loadB(bq[0], 0, 0);

#pragma unroll 1
  for (int it = 0; it < KITER; ++it) {
    const int c = it & 1;
    if (it + 1 < KITER) stage(c ^ 1, it + 1);
    // >=16 B-loads sit between stage(it) and here in program order, and
    // vmcnt retires in order, so vmcnt(8) guarantees stage(it) landed
    // while keeping the next tile's A-stage + next B-loads in flight.
    asm volatile("s_waitcnt vmcnt(8)" ::: "memory");
    __builtin_amdgcn_s_barrier();
#pragma unroll
    for (int ks = 0; ks < 4; ks++) {
      // issue B fragments for the next ks-phase (or next tile's ks0)
      const int nit = (ks == 3) ? ((it + 1 < KITER) ? it + 1 : it) : it;
      const int nks = (ks == 3) ? 0 : ks + 1;
      loadB(bq[(ks + 1) & 1], nit, nks);
      const int cc = 2 * ks + hh;
      half8 af[2];
#pragma unroll
      for (int mb = 0; mb < 2; mb++) {
        const int r = wm * 64 + mb * 32 + r32;
        af[mb] = *(const half8*)(&As[c][r * 64 + ((cc + r) & 7) * 8]);
      }
      __builtin_amdgcn_s_setprio(1);
#pragma unroll
      for (int mb = 0; mb < 2; mb++)
#pragma unroll
        for (int nb = 0; nb < 4; nb++)
          acc[mb][nb] = __builtin_amdgcn_mfma_f32_32x32x16_f16(
              af[mb], bq[ks & 1][nb], acc[mb][nb], 0, 0, 0);
      __builtin_amdgcn_s_setprio(0);
    }
    __builtin_amdgcn_s_barrier();
  }

  // Epilogue. C/D layout (32x32): col = lane&31, row = (reg&3)+8*(reg>>2)+4*hh.
  // Wave M-span = 64 rows = 1 image x 64 channels: img = mtile*4 + wm,
  // channel = mb*32 + row. Contract channels with Wc, bias, ELU.
  const int img = mtile * 4 + wm;
  const int nbase = tileN + wn * 128;
#pragma unroll
  for (int nb = 0; nb < 4; nb++) {
    const int n_g = nbase + nb * 32 + r32;
    const float* wc = Wc + (size_t)n_g * NCONV;
    float p = 0.f;
#pragma unroll
    for (int mb = 0; mb < 2; mb++)
#pragma unroll
      for (int g = 0; g < 4; g++) {
        const f32x4 w = *(const f32x4*)(wc + mb * 32 + hh * 4 + g * 8);
#pragma unroll
        for (int q = 0; q < 4; q++)
          p += acc[mb][nb][g * 4 + q] * w[q];
      }
    p += __shfl_xor(p, 32);  // combine the two hh channel-halves
    if (hh == 0) {
      float z = p * 0.00390625f + bias[n_g];  // undo x256 scaling
      z = z > 0.f ? z : (__expf(z) - 1.f);
      out[(size_t)img * NNEUR + n_g] = z;
    }
  }
}

extern "C" void kernel_launch(void* const* d_in, const int* in_sizes, int n_in,
                              void* d_out, int out_size, void* d_ws,
                              size_t ws_size, hipStream_t stream) {
  const float* conv = (const float*)d_in[0];
  const float* Wc = (const float*)d_in[1];
  const float* Wy = (const float*)d_in[2];
  const float* Wx = (const float*)d_in[3];
  const float* bias = (const float*)d_in[4];
  float* out = (float*)d_out;

  _Float16* Abuf = (_Float16*)d_ws;                                      // 44.0 MB
  _Float16* Bbuf = (_Float16*)((char*)d_ws + (size_t)MROWS * KPAD * 2);  // 22.0 MB

  prep_kernel<<<dim3(252, 64), 256, 0, stream>>>(conv, Wy, Wx, Abuf, Bbuf);
  gemm_fused_kernel<<<2048, 512, 0, stream>>>(Abuf, Bbuf, Wc, bias, out);
}

// Round 3
// 562.544 us; speedup vs baseline: 1.5259x; 1.5259x over previous
//
#include <hip/hip_runtime.h>
#include <hip/hip_bf16.h>

// Problem constants
#define NNEUR 8192
#define NCONV 64
#define LYC   36
#define LXC   36
#define BATCH 256
#define KRAW  1296   // 36*36
#define KPAD  1344   // 21*64
#define KITER 21     // KPAD/64
#define MROWS 16384  // BATCH*NCONV
#define BM 256
#define BN 256
#define BK 64
// One K-tile image per operand per iter: 2048 chunks of 16B = 32 KB.
#define A_IT_H   16384                 // halfs per (tile, it)
#define A_TILE_H (KITER * A_IT_H)      // 344064 halfs = 672 KB
#define B_TILE_H (KITER * A_IT_H)      // same (256-row n-tiles)

typedef __attribute__((ext_vector_type(8))) _Float16 half8;
typedef __attribute__((ext_vector_type(4))) float f32x4;
typedef __attribute__((ext_vector_type(16))) float f32x16;

__device__ __forceinline__ void async_copy16(const void* g, void* l) {
  __builtin_amdgcn_global_load_lds(
      (const __attribute__((address_space(1))) void*)g,
      (__attribute__((address_space(3))) void*)l, 16, 0, 0);
}

// Prep: emit A (conv->f16) and B (Wy*Wx*256->f16) in the GEMM's staged
// LDS-image order with the bank-XOR swizzle baked in. Image layout per
// (tile, it): halfs offset (r*8 + s)*8 holds source chunk c = (s - r)&7 of
// row r. Identical images to the round-1 (verified) prep; B inner loop
// uses one divide + incremental (y,x) walk instead of 8 divides.
// grid: x = 0..167 -> A (it = x>>3, i = x&7, mtile = y);
//       x = 168..251 -> B (x'=x-168, it = x'>>2, i4 = x'&3,
//                          ntile = y>>1, row-half = y&1).
__global__ __launch_bounds__(256) void prep_kernel(
    const float* __restrict__ conv, const float* __restrict__ Wy,
    const float* __restrict__ Wx, _Float16* __restrict__ A,
    _Float16* __restrict__ B) {
  const int t = threadIdx.x;
  const int bx = blockIdx.x;
  const int slot = t & 7;
  half8 h;
  if (bx < 168) {  // A part (swizzled image, unchanged)
    const int tile = blockIdx.y;
    const int it = bx >> 3, i = bx & 7;
    const int r = (t >> 3) + 32 * i;                 // row in tile, 0..255
    const int c = (slot - r) & 7;                    // source chunk
    const int k0 = it * 64 + c * 8;
    const int grow = tile * BM + r;
    if (k0 < KRAW) {
      const float* s = conv + (size_t)grow * KRAW + k0;
#pragma unroll
      for (int e = 0; e < 8; e++) h[e] = (_Float16)s[e];
    } else {
#pragma unroll
      for (int e = 0; e < 8; e++) h[e] = (_Float16)0.f;
    }
    *(half8*)(A + (size_t)tile * A_TILE_H + ((size_t)bx * 256 + t) * 8) = h;
  } else {  // B part: 256-row n-tiles, swizzled like A
    const int bxp = bx - 168;                        // 0..83
    const int it = bxp >> 2, i4 = bxp & 3;           // it 0..20
    const int yb = blockIdx.y & 1;
    const int ntile = blockIdx.y >> 1;               // 0..31
    const int r = (t >> 3) + 32 * i4 + 128 * yb;     // row in tile, 0..255
    const int c = (slot - r) & 7;
    const int k0 = it * 64 + c * 8;
    const int n = ntile * BN + r;
    const float* wyn = Wy + n * LYC;
    const float* wxn = Wx + n * LXC;
    int y = k0 / LXC;
    int x = k0 - y * LXC;
#pragma unroll
    for (int e = 0; e < 8; e++) {
      const int k = k0 + e;
      float v = 0.f;
      if (k < KRAW) v = wyn[y] * wxn[x] * 256.f;
      h[e] = (_Float16)v;
      if (++x == LXC) { x = 0; ++y; }
    }
    // staged position p = r*8 + slot = yb*1024 + i4*256 + t
    *(half8*)(B + (size_t)ntile * B_TILE_H + (size_t)it * A_IT_H +
              (size_t)(yb * 1024 + i4 * 256 + t) * 8) = h;
  }
}

// Fused GEMM, 8-phase counted-vmcnt schedule (m201-style T3+T4+T5):
// block tile 256(M)x256(N), BK=64, 8 waves (2M x 4N), wave tile 128x64 =
// [4 mb][2 nb] of 32x32x16 f16 MFMA (acc 8 x f32x16 = 128 AGPR).
// LDS 128 KB: A,B double-buffered. Per K-tile: stage next tile's 8 copies,
// s_waitcnt vmcnt(8) (waits only the previous stage; next stays in flight
// -- never drains to 0 in the main loop), data-ready barrier, then 4
// phases of {6 ds_read_b128 -> barrier -> lgkmcnt(0) -> setprio(1) ->
// 8 MFMA -> setprio(0) -> barrier}. Epilogue: Wc contraction, bias, ELU.
__global__ __launch_bounds__(512, 2) void gemm_fused_kernel(
    const _Float16* __restrict__ A, const _Float16* __restrict__ B,
    const float* __restrict__ Wc, const float* __restrict__ bias,
    float* __restrict__ out) {
  __shared__ _Float16 As[2][BM * BK];  // 2 x 32 KB
  __shared__ _Float16 Bs[2][BN * BK];  // 2 x 32 KB

  // Bijective XCD swizzle (2048 % 8 == 0): each XCD gets 256 consecutive
  // gids = 8 mtiles x 32 ntiles; B panel slice L2-resident per XCD.
  const int bid = blockIdx.x;              // 0..2047
  const int gid = (bid & 7) * 256 + (bid >> 3);
  const int mtile = gid >> 5;              // 0..63
  const int ntile = gid & 31;              // 0..31
  const int tileN = ntile * BN;

  const int t = threadIdx.x;
  const int lane = t & 63;
  const int wave = t >> 6;
  const int wm = wave >> 2, wn = wave & 3;  // 2x4 waves; wave tile 128x64
  const int r32 = lane & 31, hh = lane >> 5;

  f32x16 acc[4][2] = {};  // [mb][nb]

  const _Float16* pA = A + (size_t)mtile * A_TILE_H + t * 8;
  const _Float16* pB = B + (size_t)ntile * B_TILE_H + t * 8;

  auto stage = [&](int b, int it) {
    const _Float16* sA = pA + it * A_IT_H;
    const _Float16* sB = pB + it * A_IT_H;
    _Float16* lA = &As[b][t * 8];
    _Float16* lB = &Bs[b][t * 8];
#pragma unroll
    for (int i = 0; i < 4; i++) async_copy16(sA + i * 4096, lA + i * 4096);
#pragma unroll
    for (int i = 0; i < 4; i++) async_copy16(sB + i * 4096, lB + i * 4096);
  };

  auto phase = [&](int c, int ks) {
    const int cc = 2 * ks + hh;  // source chunk for this k-substep
    half8 bf[2], af[4];
#pragma unroll
    for (int nb = 0; nb < 2; nb++) {
      const int r = wn * 64 + nb * 32 + r32;
      bf[nb] = *(const half8*)(&Bs[c][r * 64 + ((cc + r) & 7) * 8]);
    }
#pragma unroll
    for (int mb = 0; mb < 4; mb++) {
      const int r = wm * 128 + mb * 32 + r32;
      af[mb] = *(const half8*)(&As[c][r * 64 + ((cc + r) & 7) * 8]);
    }
    __builtin_amdgcn_s_barrier();
    asm volatile("s_waitcnt lgkmcnt(0)" ::: "memory");
    __builtin_amdgcn_s_setprio(1);
#pragma unroll
    for (int mb = 0; mb < 4; mb++)
#pragma unroll
      for (int nb = 0; nb < 2; nb++)
        acc[mb][nb] = __builtin_amdgcn_mfma_f32_32x32x16_f16(
            af[mb], bf[nb], acc[mb][nb], 0, 0, 0);
    __builtin_amdgcn_s_setprio(0);
    __builtin_amdgcn_s_barrier();
  };

  stage(0, 0);
#pragma unroll 1
  for (int it = 0; it < KITER; ++it) {
    const int c = it & 1;
    if (it + 1 < KITER) {
      // stage(t+1) targets buf[c^1], whose tile-(t-1) reads all completed
      // before tile t-1's final phase barrier -> no LDS write/read race.
      stage(c ^ 1, it + 1);
      asm volatile("s_waitcnt vmcnt(8)" ::: "memory");  // tile t's 8 done
    } else {
      asm volatile("s_waitcnt vmcnt(0)" ::: "memory");  // drain last tile
    }
    __builtin_amdgcn_s_barrier();  // buf[c] visible to all waves
#pragma unroll
    for (int ks = 0; ks < 4; ks++) phase(c, ks);
  }

  // Epilogue. C/D layout (32x32): col = lane&31, row = (reg&3)+8*(reg>>2)+4*hh.
  // Wave rows = 128 = 2 images x 64 channels; mb pairs (0,1)->img0, (2,3)->img1;
  // channel = (mb&1)*32 + row. (Verified in rounds 0/1.)
  const int ibase = mtile * 4 + wm * 2;
  float v[2][2];  // [img][nb]
#pragma unroll
  for (int nb = 0; nb < 2; nb++) {
    const int n_g = tileN + wn * 64 + nb * 32 + r32;
    const float* wc = Wc + (size_t)n_g * NCONV;
    f32x4 w[2][4];
#pragma unroll
    for (int hf = 0; hf < 2; hf++)
#pragma unroll
      for (int g = 0; g < 4; g++)
        w[hf][g] = *(const f32x4*)(wc + hf * 32 + hh * 4 + g * 8);
#pragma unroll
    for (int img = 0; img < 2; img++) {
      float p = 0.f;
#pragma unroll
      for (int hf = 0; hf < 2; hf++)
#pragma unroll
        for (int g = 0; g < 4; g++)
#pragma unroll
          for (int q = 0; q < 4; q++)
            p += acc[img * 2 + hf][nb][g * 4 + q] * w[hf][g][q];
      p += __shfl_xor(p, 32);
      v[img][nb] = p;
    }
  }
  // Each lane writes image hh (its half), both nb; values identical per half.
  const int img = ibase + hh;
#pragma unroll
  for (int nb = 0; nb < 2; nb++) {
    const int n_out = tileN + wn * 64 + nb * 32 + r32;
    float z = v[hh][nb] * 0.00390625f + bias[n_out];  // undo x256 scaling
    z = z > 0.f ? z : (__expf(z) - 1.f);
    out[(size_t)img * NNEUR + n_out] = z;
  }
}

extern "C" void kernel_launch(void* const* d_in, const int* in_sizes, int n_in,
                              void* d_out, int out_size, void* d_ws,
                              size_t ws_size, hipStream_t stream) {
  const float* conv = (const float*)d_in[0];
  const float* Wc = (const float*)d_in[1];
  const float* Wy = (const float*)d_in[2];
  const float* Wx = (const float*)d_in[3];
  const float* bias = (const float*)d_in[4];
  float* out = (float*)d_out;

  _Float16* Abuf = (_Float16*)d_ws;                                      // 44.0 MB
  _Float16* Bbuf = (_Float16*)((char*)d_ws + (size_t)MROWS * KPAD * 2);  // 22.0 MB

  prep_kernel<<<dim3(252, 64), 256, 0, stream>>>(conv, Wy, Wx, Abuf, Bbuf);
  gemm_fused_kernel<<<2048, 512, 0, stream>>>(Abuf, Bbuf, Wc, bias, out);
}